// Round 11
// baseline (161.830 us; speedup 1.0000x reference)
//
#include <hip/hip_runtime.h>
#include <hip/hip_bf16.h>
#include <math.h>

#define N_NODES 50000
#define N_EDGES 1600000
#define D_IN 128
#define D_OUT 32
#define ALPHA 0.2f

#define NB   512     // buckets
#define RPB  98      // rows per bucket (512*98 = 50176 >= 50000)
#define HRPB 49      // rows per half-bucket
#define CAP  4096    // record slots per bucket (mean ~3125, 17 sigma margin)
#define CAPH 2048    // staged slots per half-bucket (mean ~1563, 12 sigma)
#define PT   16      // edges per thread in bucketize path
#define PBK  256     // threads per bucketize block (== K1 block size)
#define EB   (PT * PBK)                     // 4096 edges per bucketize block
#define XNPB 32      // nodes per GEMM block
#define NXB  ((N_NODES + XNPB - 1) / XNPB)  // 1563 GEMM blocks
#define NPB  ((N_EDGES + EB - 1) / EB)      // 391 bucketize blocks
#define OSTR 128     // gOff ints per bucket (99 used)

// Monotone float<->int key (involution). Works with signed atomicMin/Max.
__device__ __forceinline__ int enc_f(float x) {
    int i = __float_as_int(x);
    return i >= 0 ? i : (i ^ 0x7fffffff);
}
__device__ __forceinline__ float dec_f(int k) {
    return __int_as_float(k >= 0 ? k : (k ^ 0x7fffffff));
}
__device__ __forceinline__ unsigned short f2bf(float x) {
    __hip_bfloat16 h = __float2bfloat16(x);
    return *(unsigned short*)&h;
}
__device__ __forceinline__ float bf2f(unsigned short u) {
    return __uint_as_float((unsigned)u << 16);
}

// K1: heterogeneous fused dispatch.
// Blocks [0, NXB):        GEMM  X@W -> Xpb(bf16), s0, s1 (fp32 accum).
// Blocks [NXB, NXB+NPB):  bucketize edges -> 4B records {lr:7|col:16} into
//                         per-bucket regions (no s0/s1 dependency!).
// The two halves are independent and co-resident -> the bucketize memory
// phase overlaps the GEMM's DS/VALU phase. gcount pre-zeroed by memset.
__global__ __launch_bounds__(256) void k_fused(const float* __restrict__ X,
                                               const float* __restrict__ W,
                                               const float* __restrict__ a0,
                                               const float* __restrict__ a1,
                                               const int* __restrict__ row,
                                               const int* __restrict__ col,
                                               unsigned short* __restrict__ Xpb,
                                               float* __restrict__ s0,
                                               float* __restrict__ s1,
                                               int* __restrict__ minmax,
                                               int* __restrict__ gcount,
                                               unsigned* __restrict__ gEdges) {
    __shared__ char smem[32768] __attribute__((aligned(16))); // union: GEMM 32KB / bucketize 4KB+
    const int tid = threadIdx.x;
    if (blockIdx.x < NXB) {
        // ---------------- GEMM path (identical math to R10 k_xw) ----------
        float4* Wl4 = (float4*)smem;             // 1024 float4 = 16 KB
        float4* Xl4 = (float4*)(smem + 16384);   // 1024 float4 = 16 KB
        if (blockIdx.x == 0 && tid == 0) {
            minmax[0] = 0x7fffffff; // running min key (consumed by K2 atomics)
            minmax[1] = 0x80000000; // running max key
        }
        const int node0 = blockIdx.x * XNPB;
        {
            const float4* W4 = (const float4*)W;
#pragma unroll
            for (int i = 0; i < 4; ++i) Wl4[tid + 256 * i] = W4[tid + 256 * i];
            const float4* X4 = (const float4*)X + (size_t)node0 * (D_IN / 4);
            const int lim = (min(XNPB, N_NODES - node0)) * (D_IN / 4);
#pragma unroll
            for (int i = 0; i < 4; ++i) {
                const int idx = tid + 256 * i;
                Xl4[idx] = (idx < lim) ? X4[idx] : make_float4(0.f, 0.f, 0.f, 0.f);
            }
        }
        __syncthreads();

        const int g = tid >> 3;  // node within block (0..31)
        const int l = tid & 7;   // lane -> dims [4l, 4l+4)
        const int node = node0 + g;
        const float4* xr = &Xl4[g * (D_IN / 4)];
        float ax = 0.f, ay = 0.f, az = 0.f, aw = 0.f;
#pragma unroll 4
        for (int kk = 0; kk < D_IN / 4; ++kk) {
            const float4 xv = xr[kk];
            const float4 w0 = Wl4[(4 * kk + 0) * 8 + l];
            const float4 w1 = Wl4[(4 * kk + 1) * 8 + l];
            const float4 w2 = Wl4[(4 * kk + 2) * 8 + l];
            const float4 w3 = Wl4[(4 * kk + 3) * 8 + l];
            ax += xv.x * w0.x + xv.y * w1.x + xv.z * w2.x + xv.w * w3.x;
            ay += xv.x * w0.y + xv.y * w1.y + xv.z * w2.y + xv.w * w3.y;
            az += xv.x * w0.z + xv.y * w1.z + xv.z * w2.z + xv.w * w3.z;
            aw += xv.x * w0.w + xv.y * w1.w + xv.z * w2.w + xv.w * w3.w;
        }
        if (node < N_NODES) {
            uint2 pk;
            pk.x = ((unsigned)f2bf(ay) << 16) | f2bf(ax);
            pk.y = ((unsigned)f2bf(aw) << 16) | f2bf(az);
            ((uint2*)Xpb)[(size_t)node * 8 + l] = pk;
        }
        const float4 A0 = ((const float4*)a0)[l];
        const float4 A1 = ((const float4*)a1)[l];
        float v0 = ax * A0.x + ay * A0.y + az * A0.z + aw * A0.w;
        float v1 = ax * A1.x + ay * A1.y + az * A1.z + aw * A1.w;
#pragma unroll
        for (int m = 4; m >= 1; m >>= 1) {
            v0 += __shfl_xor(v0, m);
            v1 += __shfl_xor(v1, m);
        }
        if (l == 0 && node < N_NODES) { s0[node] = v0; s1[node] = v1; }
    } else {
        // ---------------- bucketize path (no score, no s0/s1) -------------
        int* hist = (int*)smem;            // NB ints = 2 KB
        int* lcur = (int*)(smem + 2048);   // NB ints = 2 KB
        const int bb = blockIdx.x - NXB;
        for (int i = tid; i < NB; i += PBK) hist[i] = 0;
        __syncthreads();
        const int base = bb * EB;
        unsigned px[PT]; // (b:9 | lr:7 | col:16)
        int cnt = 0;
        if (base + EB <= N_EDGES) { // full block: int4 vector loads
#pragma unroll
            for (int i = 0; i < PT / 4; ++i) {
                const int4 r4 = ((const int4*)(row + base))[tid + i * PBK];
                const int4 c4 = ((const int4*)(col + base))[tid + i * PBK];
                const int rr[4] = {r4.x, r4.y, r4.z, r4.w};
                const int cc[4] = {c4.x, c4.y, c4.z, c4.w};
#pragma unroll
                for (int j = 0; j < 4; ++j) {
                    const unsigned b = (unsigned)rr[j] / RPB;
                    const unsigned lr = (unsigned)rr[j] - b * RPB;
                    px[cnt++] = (b << 23) | (lr << 16) | (unsigned)cc[j];
                    atomicAdd(&hist[b], 1);
                }
            }
        } else {                    // tail block: scalar guarded
#pragma unroll
            for (int i = 0; i < PT; ++i) {
                const int e = base + i * PBK + tid;
                if (e >= N_EDGES) break;
                const int r = row[e];
                const unsigned b = (unsigned)r / RPB;
                const unsigned lr = (unsigned)r - b * RPB;
                px[cnt++] = (b << 23) | (lr << 16) | (unsigned)col[e];
                atomicAdd(&hist[b], 1);
            }
        }
        __syncthreads();
        for (int i = tid; i < NB; i += PBK) {
            const int h = hist[i];
            lcur[i] = h > 0 ? atomicAdd(&gcount[i], h) : 0;
        }
        __syncthreads();
        for (int j = 0; j < cnt; ++j) {
            const unsigned p = px[j];
            const unsigned b = p >> 23;
            const int pos = atomicAdd(&lcur[b], 1);
            if (pos < CAP) gEdges[(size_t)b * CAP + pos] = p & 0x7FFFFFu;
        }
    }
}

// K2: one block per bucket. Traverse the bucket's records once:
// min/max of leaky(s0[r]+s1[c]) (s0 from a 98-entry LDS stage -> only s1 is
// a random gather) AND per-row histogram -> CDF written to gOff (so K3 can
// skip its histogram pass entirely).
__global__ __launch_bounds__(512) void k_minmax(const int* __restrict__ gcount,
                                                const unsigned* __restrict__ gEdges,
                                                const float* __restrict__ s0,
                                                const float* __restrict__ s1,
                                                int* __restrict__ minmax,
                                                int* __restrict__ gOff) {
    __shared__ float s0l[RPB];
    __shared__ int hist[RPB];
    __shared__ int smn[8], smx[8];
    const int b = blockIdx.x;
    const int t = threadIdx.x;
    if (t < RPB) {
        const int r = b * RPB + t;
        s0l[t] = (r < N_NODES) ? s0[r] : 0.f;
        hist[t] = 0;
    }
    __syncthreads();
    const int cnt = min(gcount[b], CAP);
    const unsigned* eb = gEdges + (size_t)b * CAP;
    int kmin = 0x7fffffff, kmax = 0x80000000;
    for (int i = t; i < cnt; i += 512) {
        const unsigned e = eb[i];
        const int lr = (int)(e >> 16);
        const unsigned c = e & 0xFFFFu;
        float a = s0l[lr] + s1[c];
        a = a > 0.f ? a : ALPHA * a;
        const int k = enc_f(a);
        kmin = min(kmin, k);
        kmax = max(kmax, k);
        atomicAdd(&hist[lr], 1);
    }
#pragma unroll
    for (int m = 32; m >= 1; m >>= 1) {
        kmin = min(kmin, __shfl_xor(kmin, m));
        kmax = max(kmax, __shfl_xor(kmax, m));
    }
    const int wave = t >> 6;
    if ((t & 63) == 0) { smn[wave] = kmin; smx[wave] = kmax; }
    __syncthreads();
    if (t == 0) {
#pragma unroll
        for (int w = 1; w < 8; ++w) {
            kmin = min(kmin, smn[w]);
            kmax = max(kmax, smx[w]);
        }
        atomicMin(&minmax[0], kmin);
        atomicMax(&minmax[1], kmax);
        int run = 0;
        for (int r = 0; r < RPB; ++r) { gOff[b * OSTR + r] = run; run += hist[r]; }
        gOff[b * OSTR + RPB] = run;
    }
}

// K3: one 512-thread block per HALF-bucket (1024 blocks, ~13 KB LDS ->
// 4 blocks/CU). Histogram pass ELIMINATED (CDF loaded from gOff):
// pass: counting-sort scatter, w = exp(minmaxnorm(leaky(s0[r]+s1[c])))
//       computed once per edge;
// rows: 16 row-processors x 32 lanes walk each row's contiguous segment,
//       4-way unrolled register accumulators, one 64B bf16 Xp line per
//       edge; out = acc/wsum written directly.
__global__ __launch_bounds__(512, 8) void k_bucket(const int* __restrict__ gcount,
                                                   const unsigned* __restrict__ gEdges,
                                                   const unsigned short* __restrict__ Xpb,
                                                   const float* __restrict__ s0,
                                                   const float* __restrict__ s1,
                                                   const int* __restrict__ minmax,
                                                   const int* __restrict__ gOff,
                                                   float* __restrict__ out) {
    __shared__ unsigned short scol[CAPH]; // 4 KB
    __shared__ float swt[CAPH];           // 8 KB
    __shared__ float s0l[HRPB];
    __shared__ int offl[HRPB + 1];        // absolute CDF within bucket
    __shared__ int cur[HRPB];             // local write cursors
    const int bid = blockIdx.x;
    const int b = bid >> 1;
    const int lo = (bid & 1) * HRPB;
    const int t = threadIdx.x;
    const float mn = dec_f(minmax[0]);
    const float mx = dec_f(minmax[1]);
    const float inv = 1.0f / (mx - mn);
    const int cnt = min(gcount[b], CAP);
    const unsigned* eb = gEdges + (size_t)b * CAP;

    if (t <= HRPB) offl[t] = gOff[b * OSTR + lo + t];
    if (t < HRPB) {
        const int r = b * RPB + lo + t;
        s0l[t] = (r < N_NODES) ? s0[r] : 0.f;
    }
    __syncthreads();
    const int base0 = offl[0];
    if (t < HRPB) cur[t] = offl[t] - base0;
    __syncthreads();
    // counting-sort scatter, w computed once per edge
    for (int i = t; i < cnt; i += 512) {
        const unsigned e = eb[i];
        const int lrl = (int)(e >> 16) - lo;
        if ((unsigned)lrl < (unsigned)HRPB) {
            const unsigned c = e & 0xFFFFu;
            float a = s0l[lrl] + s1[c];
            a = a > 0.f ? a : ALPHA * a;
            const int p = atomicAdd(&cur[lrl], 1);
            if (p < CAPH) {
                scol[p] = (unsigned short)c;
                swt[p] = __expf((a - mn) * inv);
            }
        }
    }
    __syncthreads();

    // row processing: 16 processors x 32 lanes, 4-way unrolled reg accumulation
    const int proc = t >> 5;  // 0..15
    const int d = t & 31;     // output dim
    for (int lrl = proc; lrl < HRPB; lrl += 16) {
        const int s = min(offl[lrl] - base0, CAPH);
        const int e2 = min(offl[lrl + 1] - base0, CAPH);
        float ac0 = 0.f, ac1 = 0.f, ac2 = 0.f, ac3 = 0.f;
        float w0s = 0.f, w1s = 0.f, w2s = 0.f, w3s = 0.f;
        int i = s;
        for (; i + 3 < e2; i += 4) {
            const int c0 = scol[i];
            const int c1 = scol[i + 1];
            const int c2 = scol[i + 2];
            const int c3 = scol[i + 3];
            const float w0 = swt[i];
            const float w1 = swt[i + 1];
            const float w2 = swt[i + 2];
            const float w3 = swt[i + 3];
            ac0 += w0 * bf2f(Xpb[(size_t)c0 * D_OUT + d]);
            ac1 += w1 * bf2f(Xpb[(size_t)c1 * D_OUT + d]);
            ac2 += w2 * bf2f(Xpb[(size_t)c2 * D_OUT + d]);
            ac3 += w3 * bf2f(Xpb[(size_t)c3 * D_OUT + d]);
            w0s += w0; w1s += w1; w2s += w2; w3s += w3;
        }
        for (; i < e2; ++i) {
            const float w0 = swt[i];
            ac0 += w0 * bf2f(Xpb[(size_t)scol[i] * D_OUT + d]);
            w0s += w0;
        }
        const int r = b * RPB + lo + lrl;
        if (r < N_NODES)
            out[(size_t)r * D_OUT + d] =
                (ac0 + ac1 + ac2 + ac3) / (w0s + w1s + w2s + w3s);
    }
}

extern "C" void kernel_launch(void* const* d_in, const int* in_sizes, int n_in,
                              void* d_out, int out_size, void* d_ws, size_t ws_size,
                              hipStream_t stream) {
    const float* X  = (const float*)d_in[0];
    const float* W  = (const float*)d_in[1];
    const float* a0 = (const float*)d_in[2];
    const float* a1 = (const float*)d_in[3];
    const int* row  = (const int*)d_in[4];
    const int* col  = (const int*)d_in[5];
    float* out = (float*)d_out;

    // Workspace layout (4B units):
    // [minmax: 64][gcount: 2048][gOff: 512*128][s0: 50048][s1: 50048]
    // [Xpb: 1.6M u16 = 800000 u32][gEdges: NB*CAP u32]
    float* ws = (float*)d_ws;
    int*   minmax = (int*)ws;
    int*   gcount = (int*)(ws + 64);
    int*   gOff   = (int*)(ws + 64 + 2048);
    float* s0 = ws + 64 + 2048 + NB * OSTR;
    float* s1 = s0 + 50048;
    unsigned short* Xpb = (unsigned short*)(s1 + 50048); // 16B-aligned
    unsigned* gEdges = (unsigned*)(s1 + 50048 + 800000); // after 1.6M u16

    hipMemsetAsync(gcount, 0, NB * sizeof(int), stream);
    k_fused<<<NXB + NPB, 256, 0, stream>>>(X, W, a0, a1, row, col, Xpb, s0, s1,
                                           minmax, gcount, gEdges);
    k_minmax<<<NB, 512, 0, stream>>>(gcount, gEdges, s0, s1, minmax, gOff);
    k_bucket<<<NB * 2, 512, 0, stream>>>(gcount, gEdges, Xpb, s0, s1, minmax,
                                         gOff, out);
}

// Round 13
// 155.647 us; speedup vs baseline: 1.0397x; 1.0397x over previous
//
#include <hip/hip_runtime.h>
#include <hip/hip_bf16.h>
#include <math.h>

#define N_NODES 50000
#define N_EDGES 1600000
#define D_IN 128
#define D_OUT 32
#define ALPHA 0.2f

#define NB   512     // buckets
#define RPB  98      // rows per bucket (512*98 = 50176 >= 50000)
#define HRPB 49      // rows per half-bucket
#define CAP  4096    // record slots per bucket (mean ~3125, 17 sigma)
#define CAPH 2048    // staged slots per half-bucket (mean ~1563, 12 sigma)
#define PT   16      // edges per thread in edge path
#define PBK  256     // K2 block size
#define EB   (PT * PBK)                     // 4096 edges per edge-block
#define XNPB 32      // nodes per GEMM block
#define NXB  ((N_NODES + XNPB - 1) / XNPB)  // 1563 GEMM blocks
#define NPB  ((N_EDGES + EB - 1) / EB)      // 391 edge blocks
#define SNPB 32      // nodes per k_s block

// Monotone float<->int key (involution). Works with signed atomicMin/Max.
__device__ __forceinline__ int enc_f(float x) {
    int i = __float_as_int(x);
    return i >= 0 ? i : (i ^ 0x7fffffff);
}
__device__ __forceinline__ float dec_f(int k) {
    return __int_as_float(k >= 0 ? k : (k ^ 0x7fffffff));
}
__device__ __forceinline__ unsigned short f2bf(float x) {
    __hip_bfloat16 h = __float2bfloat16(x);
    return *(unsigned short*)&h;
}
__device__ __forceinline__ float bf2f(unsigned short u) {
    return __uint_as_float((unsigned)u << 16);
}

// K1: s0 = X @ (W@a0), s1 = X @ (W@a1) — GEMV, no full GEMM needed.
// 32 nodes per 256-thread block, 8 lanes per node (coalesced 512B/row).
// Block 0 also inits gcount + minmax (absorbs the memset dispatch).
__global__ __launch_bounds__(256) void k_s(const float* __restrict__ X,
                                           const float* __restrict__ W,
                                           const float* __restrict__ a0,
                                           const float* __restrict__ a1,
                                           float* __restrict__ s0,
                                           float* __restrict__ s1,
                                           int* __restrict__ minmax,
                                           int* __restrict__ gcount) {
    __shared__ float wa0[D_IN], wa1[D_IN];
    const int tid = threadIdx.x;
    if (blockIdx.x == 0) {
        if (tid == 0) {
            minmax[0] = 0x7fffffff;      // running min key
            minmax[1] = (int)0x80000000; // running max key
        }
        for (int i = tid; i < NB; i += 256) gcount[i] = 0;
    }
    {   // wa0/wa1: W row k dotted with a0/a1 (redundant per block, L2-hot)
        const int k = tid & 127;
        const float4* Wr = (const float4*)(W + k * D_OUT);
        const float4* A = (const float4*)((tid < 128) ? a0 : a1);
        float acc = 0.f;
#pragma unroll
        for (int j = 0; j < 8; ++j) {
            const float4 w = Wr[j];
            const float4 a = A[j];
            acc += w.x * a.x + w.y * a.y + w.z * a.z + w.w * a.w;
        }
        if (tid < 128) wa0[k] = acc; else wa1[k] = acc;
    }
    __syncthreads();
    const int node = blockIdx.x * SNPB + (tid >> 3);
    const int l = tid & 7;  // lane -> k-range [16l, 16l+16)
    if (node < N_NODES) {
        const float4* xr = (const float4*)(X + (size_t)node * D_IN) + l * 4;
        const float4* p4 = (const float4*)wa0 + l * 4;
        const float4* q4 = (const float4*)wa1 + l * 4;
        float v0 = 0.f, v1 = 0.f;
#pragma unroll
        for (int j = 0; j < 4; ++j) {
            const float4 x = xr[j];
            const float4 p = p4[j];
            const float4 q = q4[j];
            v0 += x.x * p.x + x.y * p.y + x.z * p.z + x.w * p.w;
            v1 += x.x * q.x + x.y * q.y + x.z * q.z + x.w * q.w;
        }
#pragma unroll
        for (int m = 4; m >= 1; m >>= 1) {
            v0 += __shfl_xor(v0, m);
            v1 += __shfl_xor(v1, m);
        }
        if (l == 0) { s0[node] = v0; s1[node] = v1; }
    }
}

// K2: heterogeneous fused dispatch.
// Blocks [0, NXB):       GEMM X@W -> Xpb (bf16). No s0/s1 (K1 did them).
// Blocks [NXB, NXB+NPB): edge pass: score = leaky(s0[r]+s1[c]) (s0/s1 from
//                        K1, L2-resident), global minmax, bucketize into 8B
//                        scored records {lr:7|col:16, score}. Independent of
//                        the GEMM -> overlaps it.
__global__ __launch_bounds__(256) void k_fused(const float* __restrict__ X,
                                               const float* __restrict__ W,
                                               const int* __restrict__ row,
                                               const int* __restrict__ col,
                                               const float* __restrict__ s0,
                                               const float* __restrict__ s1,
                                               unsigned short* __restrict__ Xpb,
                                               int* __restrict__ minmax,
                                               int* __restrict__ gcount,
                                               uint2* __restrict__ gEdges) {
    __shared__ char smem[32768] __attribute__((aligned(16)));
    const int tid = threadIdx.x;
    if (blockIdx.x < NXB) {
        // ---------------- GEMM path (R11-validated) ----------------
        float4* Wl4 = (float4*)smem;             // 16 KB
        float4* Xl4 = (float4*)(smem + 16384);   // 16 KB
        const int node0 = blockIdx.x * XNPB;
        {
            const float4* W4 = (const float4*)W;
#pragma unroll
            for (int i = 0; i < 4; ++i) Wl4[tid + 256 * i] = W4[tid + 256 * i];
            const float4* X4 = (const float4*)X + (size_t)node0 * (D_IN / 4);
            const int lim = (min(XNPB, N_NODES - node0)) * (D_IN / 4);
#pragma unroll
            for (int i = 0; i < 4; ++i) {
                const int idx = tid + 256 * i;
                Xl4[idx] = (idx < lim) ? X4[idx] : make_float4(0.f, 0.f, 0.f, 0.f);
            }
        }
        __syncthreads();
        const int g = tid >> 3;  // node within block (0..31)
        const int l = tid & 7;   // lane -> dims [4l, 4l+4)
        const int node = node0 + g;
        const float4* xr = &Xl4[g * (D_IN / 4)];
        float ax = 0.f, ay = 0.f, az = 0.f, aw = 0.f;
#pragma unroll 4
        for (int kk = 0; kk < D_IN / 4; ++kk) {
            const float4 xv = xr[kk];
            const float4 w0 = Wl4[(4 * kk + 0) * 8 + l];
            const float4 w1 = Wl4[(4 * kk + 1) * 8 + l];
            const float4 w2 = Wl4[(4 * kk + 2) * 8 + l];
            const float4 w3 = Wl4[(4 * kk + 3) * 8 + l];
            ax += xv.x * w0.x + xv.y * w1.x + xv.z * w2.x + xv.w * w3.x;
            ay += xv.x * w0.y + xv.y * w1.y + xv.z * w2.y + xv.w * w3.y;
            az += xv.x * w0.z + xv.y * w1.z + xv.z * w2.z + xv.w * w3.z;
            aw += xv.x * w0.w + xv.y * w1.w + xv.z * w2.w + xv.w * w3.w;
        }
        if (node < N_NODES) {
            uint2 pk;
            pk.x = ((unsigned)f2bf(ay) << 16) | f2bf(ax);
            pk.y = ((unsigned)f2bf(aw) << 16) | f2bf(az);
            ((uint2*)Xpb)[(size_t)node * 8 + l] = pk;
        }
    } else {
        // ---------------- edge path: score + minmax + bucketize ----------
        int* hist = (int*)smem;            // NB ints = 2 KB
        int* lcur = (int*)(smem + 2048);   // NB ints = 2 KB
        int* smn  = (int*)(smem + 4096);   // 4 ints
        int* smx  = (int*)(smem + 4160);   // 4 ints
        const int bb = blockIdx.x - NXB;
        for (int i = tid; i < NB; i += PBK) hist[i] = 0;
        __syncthreads();
        const int base = bb * EB;
        unsigned px[PT]; // (b:9 | lr:7 | col:16)
        float    fa[PT]; // leaky-relu'd score
        int cnt = 0;
        int kmin = 0x7fffffff, kmax = 0x80000000;
        if (base + EB <= N_EDGES) { // full block: int4 vector loads
#pragma unroll
            for (int i = 0; i < PT / 4; ++i) {
                const int4 r4 = ((const int4*)(row + base))[tid + i * PBK];
                const int4 c4 = ((const int4*)(col + base))[tid + i * PBK];
                const int rr[4] = {r4.x, r4.y, r4.z, r4.w};
                const int cc[4] = {c4.x, c4.y, c4.z, c4.w};
#pragma unroll
                for (int j = 0; j < 4; ++j) {
                    const int r = rr[j];
                    const int c = cc[j];
                    float a = s0[r] + s1[c];
                    a = a > 0.f ? a : ALPHA * a;
                    const int k = enc_f(a);
                    kmin = min(kmin, k);
                    kmax = max(kmax, k);
                    const unsigned b = (unsigned)r / RPB;
                    const unsigned lr = (unsigned)r - b * RPB;
                    px[cnt] = (b << 23) | (lr << 16) | (unsigned)c;
                    fa[cnt] = a;
                    ++cnt;
                    atomicAdd(&hist[b], 1);
                }
            }
        } else {                    // tail block: scalar guarded
#pragma unroll
            for (int i = 0; i < PT; ++i) {
                const int e = base + i * PBK + tid;
                if (e >= N_EDGES) break;
                const int r = row[e];
                const int c = col[e];
                float a = s0[r] + s1[c];
                a = a > 0.f ? a : ALPHA * a;
                const int k = enc_f(a);
                kmin = min(kmin, k);
                kmax = max(kmax, k);
                const unsigned b = (unsigned)r / RPB;
                const unsigned lr = (unsigned)r - b * RPB;
                px[cnt] = (b << 23) | (lr << 16) | (unsigned)c;
                fa[cnt] = a;
                ++cnt;
                atomicAdd(&hist[b], 1);
            }
        }
        __syncthreads();
        for (int i = tid; i < NB; i += PBK) {
            const int h = hist[i];
            lcur[i] = h > 0 ? atomicAdd(&gcount[i], h) : 0;
        }
        __syncthreads();
        for (int j = 0; j < cnt; ++j) {
            const unsigned p = px[j];
            const unsigned b = p >> 23;
            const int pos = atomicAdd(&lcur[b], 1);
            if (pos < CAP)
                gEdges[(size_t)b * CAP + pos] =
                    make_uint2(p & 0x7FFFFFu, (unsigned)__float_as_int(fa[j]));
        }
#pragma unroll
        for (int m = 32; m >= 1; m >>= 1) {
            kmin = min(kmin, __shfl_xor(kmin, m));
            kmax = max(kmax, __shfl_xor(kmax, m));
        }
        const int wave = tid >> 6;
        if ((tid & 63) == 0) { smn[wave] = kmin; smx[wave] = kmax; }
        __syncthreads();
        if (tid == 0) {
#pragma unroll
            for (int w = 1; w < 4; ++w) {
                kmin = min(kmin, smn[w]);
                kmax = max(kmax, smx[w]);
            }
            atomicMin(&minmax[0], kmin);
            atomicMax(&minmax[1], kmax);
        }
    }
}

// K3: one 512-thread block per HALF-bucket (1024 blocks, ~13 KB LDS ->
// 4 blocks/CU). Scores come from the records (no s0/s1 gathers).
// pass 1: LDS histogram of this half's rows (49 bins);
// pass 2: counting-sort scatter {col:u16, exp(minmaxnorm(score))};
// rows:   16 row-processors x 32 lanes walk each row's contiguous segment,
//         4-way unrolled register accumulators, one 64B bf16 Xp line per
//         edge; out = acc/wsum written directly.
__global__ __launch_bounds__(512, 8) void k_bucket(const int* __restrict__ gcount,
                                                   const uint2* __restrict__ gEdges,
                                                   const unsigned short* __restrict__ Xpb,
                                                   const int* __restrict__ minmax,
                                                   float* __restrict__ out) {
    __shared__ unsigned short scol[CAPH]; // 4 KB
    __shared__ float swt[CAPH];           // 8 KB
    __shared__ int off[HRPB + 1];
    __shared__ int cur[HRPB];
    const int bid = blockIdx.x;
    const int b = bid >> 1;
    const int lo = (bid & 1) * HRPB;
    const int t = threadIdx.x;
    const float mn = dec_f(minmax[0]);
    const float mx = dec_f(minmax[1]);
    const float inv = 1.0f / (mx - mn);
    const int cnt = min(gcount[b], CAP);
    const uint2* eb = gEdges + (size_t)b * CAP;

    if (t < HRPB) cur[t] = 0;  // temp hist
    __syncthreads();
    for (int i = t; i < cnt; i += 512) {
        const int lrl = (int)(eb[i].x >> 16) - lo;
        if ((unsigned)lrl < (unsigned)HRPB) atomicAdd(&cur[lrl], 1);
    }
    __syncthreads();
    if (t == 0) {
        int run = 0;
#pragma unroll
        for (int r = 0; r < HRPB; ++r) { off[r] = run; run += cur[r]; }
        off[HRPB] = run;
    }
    __syncthreads();
    if (t < HRPB) cur[t] = off[t];
    __syncthreads();
    // pass 2: counting-sort scatter (exp computed once per edge)
    for (int i = t; i < cnt; i += 512) {
        const uint2 e = eb[i];
        const int lrl = (int)(e.x >> 16) - lo;
        if ((unsigned)lrl < (unsigned)HRPB) {
            const int p = atomicAdd(&cur[lrl], 1);
            if (p < CAPH) {
                scol[p] = (unsigned short)(e.x & 0xFFFFu);
                swt[p] = __expf((__int_as_float(e.y) - mn) * inv);
            }
        }
    }
    __syncthreads();

    // row processing: 16 processors x 32 lanes, 4-way unrolled reg accumulation
    const int proc = t >> 5;  // 0..15
    const int d = t & 31;     // output dim
    for (int lrl = proc; lrl < HRPB; lrl += 16) {
        const int s = min(off[lrl], CAPH);
        const int e2 = min(off[lrl + 1], CAPH);
        float ac0 = 0.f, ac1 = 0.f, ac2 = 0.f, ac3 = 0.f;
        float w0s = 0.f, w1s = 0.f, w2s = 0.f, w3s = 0.f;
        int i = s;
        for (; i + 3 < e2; i += 4) {
            const int c0 = scol[i];
            const int c1 = scol[i + 1];
            const int c2 = scol[i + 2];
            const int c3 = scol[i + 3];
            const float w0 = swt[i];
            const float w1 = swt[i + 1];
            const float w2 = swt[i + 2];
            const float w3 = swt[i + 3];
            ac0 += w0 * bf2f(Xpb[(size_t)c0 * D_OUT + d]);
            ac1 += w1 * bf2f(Xpb[(size_t)c1 * D_OUT + d]);
            ac2 += w2 * bf2f(Xpb[(size_t)c2 * D_OUT + d]);
            ac3 += w3 * bf2f(Xpb[(size_t)c3 * D_OUT + d]);
            w0s += w0; w1s += w1; w2s += w2; w3s += w3;
        }
        for (; i < e2; ++i) {
            const float w0 = swt[i];
            ac0 += w0 * bf2f(Xpb[(size_t)scol[i] * D_OUT + d]);
            w0s += w0;
        }
        const int r = b * RPB + lo + lrl;
        if (r < N_NODES)
            out[(size_t)r * D_OUT + d] =
                (ac0 + ac1 + ac2 + ac3) / (w0s + w1s + w2s + w3s);
    }
}

extern "C" void kernel_launch(void* const* d_in, const int* in_sizes, int n_in,
                              void* d_out, int out_size, void* d_ws, size_t ws_size,
                              hipStream_t stream) {
    const float* X  = (const float*)d_in[0];
    const float* W  = (const float*)d_in[1];
    const float* a0 = (const float*)d_in[2];
    const float* a1 = (const float*)d_in[3];
    const int* row  = (const int*)d_in[4];
    const int* col  = (const int*)d_in[5];
    float* out = (float*)d_out;

    // Workspace layout (4B units):
    // [minmax: 64][gcount: 2048][s0: 50048][s1: 50048]
    // [Xpb: 1.6M u16 = 800000 u32][gEdges: NB*CAP uint2]
    float* ws = (float*)d_ws;
    int*   minmax = (int*)ws;
    int*   gcount = (int*)(ws + 64);
    float* s0 = ws + 64 + 2048;
    float* s1 = s0 + 50048;
    unsigned short* Xpb = (unsigned short*)(s1 + 50048); // 16B-aligned
    uint2* gEdges = (uint2*)(s1 + 50048 + 800000);       // after 1.6M u16

    k_s<<<(N_NODES + SNPB - 1) / SNPB, 256, 0, stream>>>(X, W, a0, a1, s0, s1,
                                                         minmax, gcount);
    k_fused<<<NXB + NPB, 256, 0, stream>>>(X, W, row, col, s0, s1, Xpb,
                                           minmax, gcount, gEdges);
    k_bucket<<<NB * 2, 512, 0, stream>>>(gcount, gEdges, Xpb, minmax, out);
}